// Round 13
// baseline (822.347 us; speedup 1.0000x reference)
//
#include <hip/hip_runtime.h>
#include <hip/hip_bf16.h>
#include <hip/hip_fp16.h>

// N = 100000 nodes, D = 64 features, E = 1250000 edges.
// Inputs: old_g[N,D] f32, W[D,D] f32, edge_weight[E,1] f32,
//         history_db[N,D] f32, src[E] i32, dst[E] i32
// Output: concat(nodes_new[N,D], history_new[N,D]) f32.
//
// Pipeline:
//  (1) LDS-tiled fp32 GEMM h = old_g @ W, stored fp16;
//  (2) bucket-append: edges appended to 521 dst-buckets (192 nodes each)
//      via per-(bucket, XCD) cursors -> appends hit consecutive addresses,
//      temporally dense -> full-line write combining in the XCD L2.
//      (Counting-sort-to-CSR was abandoned: random scatter-writes can't
//      combine regardless of window size -- R12 measurement.)
//  (3) fused per-bucket kernel: LDS acc[192][64], gather h16[src] +
//      old_g[dst] (L2-window), tanh, ds_add_f32 accumulate, write both
//      outputs once, coalesced. No srcw array, no per-dst CSR.

#define D_FEAT 64
#define BN   192          // nodes per bucket
#define APAD 68           // acc row stride in words (68%32=4 -> bank spread)
#define NK   8            // cursor sub-partitions (blockIdx&7 ~ XCD)

// ---------------------------------------------------------------------------
// K1: h = old_g @ W.  Block = 256 threads -> 128-row x 64-col tile.
// ---------------------------------------------------------------------------
#define GR 128
#define GPAD 66

__global__ __launch_bounds__(256) void gemm64_tile_kernel(
    const float* __restrict__ g, const float* __restrict__ W,
    __half* __restrict__ h16, int N) {
    __shared__ float Wl[D_FEAT * D_FEAT];
    __shared__ float Gl[GR][GPAD];

    const int tid = threadIdx.x;

    {
        const float4* w4 = reinterpret_cast<const float4*>(W);
        float4* wl4 = reinterpret_cast<float4*>(Wl);
        for (int i = tid; i < D_FEAT * D_FEAT / 4; i += 256) wl4[i] = w4[i];
    }

    const int row0  = blockIdx.x * GR;
    const int nrows = min(GR, N - row0);

    for (int i = tid; i < GR * 16; i += 256) {
        const int r  = i >> 4;
        const int c4 = i & 15;
        if (r < nrows) {
            float4 v = reinterpret_cast<const float4*>(
                           g + (size_t)(row0 + r) * D_FEAT)[c4];
            float* dp = &Gl[r][c4 * 4];
            reinterpret_cast<float2*>(dp)[0] = make_float2(v.x, v.y);
            reinterpret_cast<float2*>(dp)[1] = make_float2(v.z, v.w);
        }
    }
    __syncthreads();

    const int cg = tid & 7;
    const int rg = tid >> 3;
    const int c0 = cg * 8;
    const int r0 = rg * 4;

    float acc[4][8];
#pragma unroll
    for (int i = 0; i < 4; ++i)
#pragma unroll
        for (int j = 0; j < 8; ++j) acc[i][j] = 0.0f;

#pragma unroll 4
    for (int k = 0; k < D_FEAT; ++k) {
        const float4 wa = *reinterpret_cast<const float4*>(&Wl[k * D_FEAT + c0]);
        const float4 wb = *reinterpret_cast<const float4*>(&Wl[k * D_FEAT + c0 + 4]);
        float gv[4];
#pragma unroll
        for (int i = 0; i < 4; ++i) gv[i] = Gl[r0 + i][k];
#pragma unroll
        for (int i = 0; i < 4; ++i) {
            acc[i][0] = fmaf(gv[i], wa.x, acc[i][0]);
            acc[i][1] = fmaf(gv[i], wa.y, acc[i][1]);
            acc[i][2] = fmaf(gv[i], wa.z, acc[i][2]);
            acc[i][3] = fmaf(gv[i], wa.w, acc[i][3]);
            acc[i][4] = fmaf(gv[i], wb.x, acc[i][4]);
            acc[i][5] = fmaf(gv[i], wb.y, acc[i][5]);
            acc[i][6] = fmaf(gv[i], wb.z, acc[i][6]);
            acc[i][7] = fmaf(gv[i], wb.w, acc[i][7]);
        }
    }

#pragma unroll
    for (int i = 0; i < 4; ++i) {
        const int r = r0 + i;
        if (r < nrows) {
            __half2 hb[4];
#pragma unroll
            for (int j = 0; j < 4; ++j)
                hb[j] = __floats2half2_rn(acc[i][2 * j], acc[i][2 * j + 1]);
            *reinterpret_cast<uint4*>(h16 + (size_t)(row0 + r) * D_FEAT + c0) =
                *reinterpret_cast<uint4*>(hb);
        }
    }
}

// ---------------------------------------------------------------------------
// K2: per-(bucket, k) edge counts.  k = blockIdx&7; MUST use the identical
// edge->block mapping as pass1 so counts match exactly.
// ---------------------------------------------------------------------------
__global__ void hist_xb_kernel(const int* __restrict__ dst,
                               int* __restrict__ cnt_xb, int E) {
    const int k = blockIdx.x & (NK - 1);
    int i = blockIdx.x * blockDim.x + threadIdx.x;
    const int stride = gridDim.x * blockDim.x;
    for (; i < E; i += stride) {
        int b = dst[i] / BN;
        atomicAdd(&cnt_xb[b * NK + k], 1);
    }
}

// ---------------------------------------------------------------------------
// K3: exclusive scan of cnt_xb[M] -> base (and cur copy).  One block, 1024
// threads, 5 values each (covers M <= 5120).
// ---------------------------------------------------------------------------
__global__ __launch_bounds__(1024) void scan_xb_kernel(
    const int* __restrict__ cnt, int* __restrict__ base,
    int* __restrict__ cur, int M, int E) {
    __shared__ int lds[1024];
    const int t = threadIdx.x;
    int v[5];
    int s = 0;
#pragma unroll
    for (int i = 0; i < 5; ++i) {
        int idx = t * 5 + i;
        v[i] = (idx < M) ? cnt[idx] : 0;
        s += v[i];
    }
    lds[t] = s;
    __syncthreads();
    for (int off = 1; off < 1024; off <<= 1) {
        int x = (t >= off) ? lds[t - off] : 0;
        __syncthreads();
        lds[t] += x;
        __syncthreads();
    }
    int run = lds[t] - s;   // exclusive prefix of this thread's group
#pragma unroll
    for (int i = 0; i < 5; ++i) {
        int idx = t * 5 + i;
        if (idx < M) {
            base[idx] = run;
            cur[idx]  = run;
            run += v[i];
        }
    }
    if (t == 0) base[M] = E;
}

// ---------------------------------------------------------------------------
// K4: append edges into bucket sub-regions.  staged = {src | dstlocal<<17, w}.
// Appends to (b,k) are consecutive positions, temporally dense, one XCD ->
// full 64B-line write combining.
// ---------------------------------------------------------------------------
__global__ void pass1_kernel(const int* __restrict__ src,
                             const int* __restrict__ dst,
                             const float* __restrict__ ew,
                             int* __restrict__ cur,
                             int2* __restrict__ staged, int E) {
    const int k = blockIdx.x & (NK - 1);
    int i = blockIdx.x * blockDim.x + threadIdx.x;
    const int stride = gridDim.x * blockDim.x;
    for (; i < E; i += stride) {
        const int d  = dst[i];
        const int b  = d / BN;
        const int dl = d - b * BN;
        const int pos = atomicAdd(&cur[b * NK + k], 1);
        staged[pos] = make_int2(src[i] | (dl << 17), __float_as_int(ew[i]));
    }
}

// ---------------------------------------------------------------------------
// K5: fused per-bucket accumulate.  Block = 256 thr = 4 waves; wave = 4
// edge-slots x 16 feature-groups; LDS acc[BN][APAD] via ds_add_f32.
// ---------------------------------------------------------------------------
__device__ __forceinline__ float fast_tanh(float x) {
    float ax = fabsf(x);
    float e  = __builtin_amdgcn_exp2f(-2.885390082f * ax);   // exp(-2|x|)
    float r  = __builtin_amdgcn_rcpf(1.0f + e);
    float t  = fmaf(-2.0f * e, r, 1.0f);                     // (1-e)/(1+e)
    return copysignf(t, x);
}

__global__ __launch_bounds__(256) void pass2_kernel(
    const __half* __restrict__ h16, const float* __restrict__ g,
    const float* __restrict__ hist, const int* __restrict__ base,
    const int2* __restrict__ staged,
    float* __restrict__ out_nodes, float* __restrict__ out_hist,
    int N, int NB) {
    __shared__ float acc[BN * APAD];
    const int tid  = threadIdx.x;
    const int lane = tid & 63;
    const int wid  = tid >> 6;
    const int slot = lane >> 4;
    const int fg   = lane & 15;

    const int b = blockIdx.x;
    if (b >= NB) return;

    for (int i = tid; i < BN * APAD; i += 256) acc[i] = 0.0f;
    __syncthreads();

    const int node0 = b * BN;
    const int nbn   = min(BN, N - node0);
    const int beg   = base[b * NK];
    const int end   = base[(b + 1) * NK];

    // each wave takes every 4th 64-edge chunk
    for (int cbase = beg + wid * 64; cbase < end; cbase += 256) {
        const int chunk = min(64, end - cbase);
        const int2 my = staged[cbase + min(lane, chunk - 1)];

        for (int g0 = 0; g0 < chunk; g0 += 8) {
            const int ia = g0 + slot;
            const int ib = ia + 4;
            const int   pa = __shfl(my.x, ia, 64);
            const float wa = __int_as_float(__shfl(my.y, ia, 64));
            const int   pb = __shfl(my.x, ib, 64);
            const float wb = __int_as_float(__shfl(my.y, ib, 64));
            const float ma = (ia < chunk) ? 1.0f : 0.0f;
            const float mb = (ib < chunk) ? 1.0f : 0.0f;
            const int sa = pa & 0x1FFFF, dla = (pa >> 17) & 255;
            const int sb = pb & 0x1FFFF, dlb = (pb >> 17) & 255;

            // issue all 4 memory ops before consuming
            const uint2  hva = *reinterpret_cast<const uint2*>(
                h16 + (size_t)sa * D_FEAT + fg * 4);
            const float4 ga  = *reinterpret_cast<const float4*>(
                g + (size_t)(node0 + dla) * D_FEAT + fg * 4);
            const uint2  hvb = *reinterpret_cast<const uint2*>(
                h16 + (size_t)sb * D_FEAT + fg * 4);
            const float4 gb  = *reinterpret_cast<const float4*>(
                g + (size_t)(node0 + dlb) * D_FEAT + fg * 4);

            {
                const float2 a0 = __half22float2(
                    *reinterpret_cast<const __half2*>(&hva.x));
                const float2 a1 = __half22float2(
                    *reinterpret_cast<const __half2*>(&hva.y));
                float* ap = &acc[dla * APAD + fg * 4];
                atomicAdd(ap + 0, ma * fast_tanh(fmaf(ga.x, wa, a0.x)));
                atomicAdd(ap + 1, ma * fast_tanh(fmaf(ga.y, wa, a0.y)));
                atomicAdd(ap + 2, ma * fast_tanh(fmaf(ga.z, wa, a1.x)));
                atomicAdd(ap + 3, ma * fast_tanh(fmaf(ga.w, wa, a1.y)));
            }
            {
                const float2 b0 = __half22float2(
                    *reinterpret_cast<const __half2*>(&hvb.x));
                const float2 b1 = __half22float2(
                    *reinterpret_cast<const __half2*>(&hvb.y));
                float* bp = &acc[dlb * APAD + fg * 4];
                atomicAdd(bp + 0, mb * fast_tanh(fmaf(gb.x, wb, b0.x)));
                atomicAdd(bp + 1, mb * fast_tanh(fmaf(gb.y, wb, b0.y)));
                atomicAdd(bp + 2, mb * fast_tanh(fmaf(gb.z, wb, b1.x)));
                atomicAdd(bp + 3, mb * fast_tanh(fmaf(gb.w, wb, b1.y)));
            }
        }
    }
    __syncthreads();

    // epilogue: coalesced write of both outputs
    const int tot = nbn * D_FEAT;
    const size_t gbase = (size_t)node0 * D_FEAT;
    for (int idx = tid; idx < tot; idx += 256) {
        const int n = idx >> 6;
        const int f = idx & 63;
        const float a = acc[n * APAD + f];
        out_nodes[gbase + idx] = a;
        out_hist[gbase + idx]  = hist[gbase + idx] + a;
    }
}

extern "C" void kernel_launch(void* const* d_in, const int* in_sizes, int n_in,
                              void* d_out, int out_size, void* d_ws, size_t ws_size,
                              hipStream_t stream) {
    const float* old_g = (const float*)d_in[0];
    const float* W     = (const float*)d_in[1];
    const float* ew    = (const float*)d_in[2];
    const float* hist  = (const float*)d_in[3];
    const int*   src   = (const int*)d_in[4];
    const int*   dst   = (const int*)d_in[5];

    const int N  = in_sizes[0] / D_FEAT;
    const int E  = in_sizes[4];
    const int ND = N * D_FEAT;
    const int NB = (N + BN - 1) / BN;      // 521
    const int M  = NB * NK;                // 4168

    float* out_nodes = (float*)d_out;
    float* out_hist  = (float*)d_out + ND;

    // Workspace layout
    char* ws = (char*)d_ws;
    __half* h16   = (__half*)ws;            ws += (size_t)ND * 2;
    int* cnt_xb   = (int*)ws;               ws += (size_t)M * 4;
    int* base     = (int*)ws;               ws += (size_t)(M + 1) * 4;
    int* cur      = (int*)ws;               ws += (size_t)M * 4;
    ws = (char*)(((uintptr_t)ws + 7) & ~(uintptr_t)7);
    int2* staged  = (int2*)ws;

    hipMemsetAsync(cnt_xb, 0, (size_t)M * sizeof(int), stream);

    // K1: h = old_g @ W (fp16 out)
    {
        int grid = (N + GR - 1) / GR;
        gemm64_tile_kernel<<<grid, 256, 0, stream>>>(old_g, W, h16, N);
    }

    // K2-K4: bucket-append build
    hist_xb_kernel<<<2048, 256, 0, stream>>>(dst, cnt_xb, E);
    scan_xb_kernel<<<1, 1024, 0, stream>>>(cnt_xb, base, cur, M, E);
    pass1_kernel<<<2048, 256, 0, stream>>>(src, dst, ew, cur, staged, E);

    // K5: fused per-bucket gather + tanh + accumulate + outputs
    pass2_kernel<<<NB, 256, 0, stream>>>(h16, old_g, hist, base, staged,
                                         out_nodes, out_hist, N, NB);
}

// Round 14
// 222.429 us; speedup vs baseline: 3.6971x; 3.6971x over previous
//
#include <hip/hip_runtime.h>
#include <hip/hip_bf16.h>
#include <hip/hip_fp16.h>

// N = 100000 nodes, D = 64 features, E = 1250000 edges.
// Inputs: old_g[N,D] f32, W[D,D] f32, edge_weight[E,1] f32,
//         history_db[N,D] f32, src[E] i32, dst[E] i32
// Output: concat(nodes_new[N,D], history_new[N,D]) f32.
//
// Pipeline (R11 structure, best measured):
//  (1) LDS-tiled fp32 GEMM h = old_g @ W, stored fp16;
//  (2) CSR-by-dst build, XCD-partitioned hist + fill (single-phase;
//      R12/R13 showed scatter write-combining is unobtainable and
//      bucket-fused LDS accumulation starves for TLP);
//  (3) node kernel: wave = 4 edge-slots x 16 feature-groups; coalesced
//      srcw chunk load (pad-safe, no clamp) + shfl broadcast; 4 gathers
//      in flight; shfl_xor slot-reduce; fused history output.

#define D_FEAT 64
#define SCAN_BLK 256
#define SCAN_CHUNK 1024   // 4 elements per thread
#define NPART 8           // = #XCDs; blockIdx%8 ~ XCD (round-robin dispatch)

// ---------------------------------------------------------------------------
// K1: h = old_g @ W.  Block = 256 threads -> 128-row x 64-col tile.
// ---------------------------------------------------------------------------
#define GR 128
#define GPAD 66

__global__ __launch_bounds__(256) void gemm64_tile_kernel(
    const float* __restrict__ g, const float* __restrict__ W,
    __half* __restrict__ h16, int N) {
    __shared__ float Wl[D_FEAT * D_FEAT];
    __shared__ float Gl[GR][GPAD];

    const int tid = threadIdx.x;

    {
        const float4* w4 = reinterpret_cast<const float4*>(W);
        float4* wl4 = reinterpret_cast<float4*>(Wl);
        for (int i = tid; i < D_FEAT * D_FEAT / 4; i += 256) wl4[i] = w4[i];
    }

    const int row0  = blockIdx.x * GR;
    const int nrows = min(GR, N - row0);

    for (int i = tid; i < GR * 16; i += 256) {
        const int r  = i >> 4;
        const int c4 = i & 15;
        if (r < nrows) {
            float4 v = reinterpret_cast<const float4*>(
                           g + (size_t)(row0 + r) * D_FEAT)[c4];
            float* dp = &Gl[r][c4 * 4];
            reinterpret_cast<float2*>(dp)[0] = make_float2(v.x, v.y);
            reinterpret_cast<float2*>(dp)[1] = make_float2(v.z, v.w);
        }
    }
    __syncthreads();

    const int cg = tid & 7;
    const int rg = tid >> 3;
    const int c0 = cg * 8;
    const int r0 = rg * 4;

    float acc[4][8];
#pragma unroll
    for (int i = 0; i < 4; ++i)
#pragma unroll
        for (int j = 0; j < 8; ++j) acc[i][j] = 0.0f;

#pragma unroll 4
    for (int k = 0; k < D_FEAT; ++k) {
        const float4 wa = *reinterpret_cast<const float4*>(&Wl[k * D_FEAT + c0]);
        const float4 wb = *reinterpret_cast<const float4*>(&Wl[k * D_FEAT + c0 + 4]);
        float gv[4];
#pragma unroll
        for (int i = 0; i < 4; ++i) gv[i] = Gl[r0 + i][k];
#pragma unroll
        for (int i = 0; i < 4; ++i) {
            acc[i][0] = fmaf(gv[i], wa.x, acc[i][0]);
            acc[i][1] = fmaf(gv[i], wa.y, acc[i][1]);
            acc[i][2] = fmaf(gv[i], wa.z, acc[i][2]);
            acc[i][3] = fmaf(gv[i], wa.w, acc[i][3]);
            acc[i][4] = fmaf(gv[i], wb.x, acc[i][4]);
            acc[i][5] = fmaf(gv[i], wb.y, acc[i][5]);
            acc[i][6] = fmaf(gv[i], wb.z, acc[i][6]);
            acc[i][7] = fmaf(gv[i], wb.w, acc[i][7]);
        }
    }

#pragma unroll
    for (int i = 0; i < 4; ++i) {
        const int r = r0 + i;
        if (r < nrows) {
            __half2 hb[4];
#pragma unroll
            for (int j = 0; j < 4; ++j)
                hb[j] = __floats2half2_rn(acc[i][2 * j], acc[i][2 * j + 1]);
            *reinterpret_cast<uint4*>(h16 + (size_t)(row0 + r) * D_FEAT + c0) =
                *reinterpret_cast<uint4*>(hb);
        }
    }
}

// ---------------------------------------------------------------------------
// CSR build — XCD-partitioned by dst range.
// ---------------------------------------------------------------------------
__global__ void hist_kernel(const int* __restrict__ dst, int* __restrict__ cnt,
                            int E, int npp) {
    const int part = blockIdx.x & (NPART - 1);
    const int lo = part * npp;
    const int hi = lo + npp;
    const int bid = blockIdx.x >> 3;
    const int nb  = gridDim.x >> 3;
    const int E4 = E >> 2;
    const int4* dst4 = reinterpret_cast<const int4*>(dst);

    int i = bid * blockDim.x + threadIdx.x;
    const int stride = nb * blockDim.x;
    for (; i < E4; i += stride) {
        int4 d = dst4[i];
        if (d.x >= lo && d.x < hi) atomicAdd(&cnt[d.x], 1);
        if (d.y >= lo && d.y < hi) atomicAdd(&cnt[d.y], 1);
        if (d.z >= lo && d.z < hi) atomicAdd(&cnt[d.z], 1);
        if (d.w >= lo && d.w < hi) atomicAdd(&cnt[d.w], 1);
    }
    for (int e = E4 * 4 + bid * blockDim.x + threadIdx.x; e < E;
         e += nb * blockDim.x) {
        int d = dst[e];
        if (d >= lo && d < hi) atomicAdd(&cnt[d], 1);
    }
}

__global__ void block_sum_kernel(const int* __restrict__ cnt, int n,
                                 int* __restrict__ blockSums) {
    __shared__ int lds[SCAN_BLK];
    const int base = blockIdx.x * SCAN_CHUNK;
    const int t = threadIdx.x;
    int s = 0;
#pragma unroll
    for (int i = 0; i < 4; ++i) {
        int idx = base + t * 4 + i;
        s += (idx < n) ? cnt[idx] : 0;
    }
    lds[t] = s;
    __syncthreads();
    for (int off = SCAN_BLK / 2; off > 0; off >>= 1) {
        if (t < off) lds[t] += lds[t + off];
        __syncthreads();
    }
    if (t == 0) blockSums[blockIdx.x] = lds[0];
}

__global__ void top_scan_kernel(int* __restrict__ blockSums, int nb) {
    if (threadIdx.x == 0 && blockIdx.x == 0) {
        int acc = 0;
        for (int i = 0; i < nb; ++i) {
            int v = blockSums[i];
            blockSums[i] = acc;
            acc += v;
        }
    }
}

__global__ void scan_fill_kernel(const int* __restrict__ cnt, int n,
                                 const int* __restrict__ blockSums,
                                 int* __restrict__ offsets,
                                 int* __restrict__ cursor, int E) {
    __shared__ int lds[SCAN_BLK];
    const int base = blockIdx.x * SCAN_CHUNK;
    const int t = threadIdx.x;
    int v[4];
    int s = 0;
#pragma unroll
    for (int i = 0; i < 4; ++i) {
        int idx = base + t * 4 + i;
        v[i] = (idx < n) ? cnt[idx] : 0;
        s += v[i];
    }
    lds[t] = s;
    __syncthreads();
    for (int off = 1; off < SCAN_BLK; off <<= 1) {
        int x = (t >= off) ? lds[t - off] : 0;
        __syncthreads();
        lds[t] += x;
        __syncthreads();
    }
    int run = lds[t] - s + blockSums[blockIdx.x];  // exclusive prefix
#pragma unroll
    for (int i = 0; i < 4; ++i) {
        int idx = base + t * 4 + i;
        if (idx < n) {
            offsets[idx] = run;
            cursor[idx]  = run;
            run += v[i];
        }
    }
    if (blockIdx.x == 0 && t == 0) offsets[n] = E;
}

__global__ void fill_kernel(const int* __restrict__ src,
                            const int* __restrict__ dst,
                            const float* __restrict__ ew,
                            int* __restrict__ cursor,
                            int2* __restrict__ srcw, int E, int npp) {
    const int part = blockIdx.x & (NPART - 1);
    const int lo = part * npp;
    const int hi = lo + npp;
    const int bid = blockIdx.x >> 3;
    const int nb  = gridDim.x >> 3;
    const int E4 = E >> 2;
    const int4* dst4 = reinterpret_cast<const int4*>(dst);

    int i = bid * blockDim.x + threadIdx.x;
    const int stride = nb * blockDim.x;
    for (; i < E4; i += stride) {
        int4 d = dst4[i];
        const int e = i * 4;
        if (d.x >= lo && d.x < hi) {
            int pos = atomicAdd(&cursor[d.x], 1);
            srcw[pos] = make_int2(src[e + 0], __float_as_int(ew[e + 0]));
        }
        if (d.y >= lo && d.y < hi) {
            int pos = atomicAdd(&cursor[d.y], 1);
            srcw[pos] = make_int2(src[e + 1], __float_as_int(ew[e + 1]));
        }
        if (d.z >= lo && d.z < hi) {
            int pos = atomicAdd(&cursor[d.z], 1);
            srcw[pos] = make_int2(src[e + 2], __float_as_int(ew[e + 2]));
        }
        if (d.w >= lo && d.w < hi) {
            int pos = atomicAdd(&cursor[d.w], 1);
            srcw[pos] = make_int2(src[e + 3], __float_as_int(ew[e + 3]));
        }
    }
    for (int e = E4 * 4 + bid * blockDim.x + threadIdx.x; e < E;
         e += nb * blockDim.x) {
        int d = dst[e];
        if (d >= lo && d < hi) {
            int pos = atomicAdd(&cursor[d], 1);
            srcw[pos] = make_int2(src[e], __float_as_int(ew[e]));
        }
    }
}

// ---------------------------------------------------------------------------
// K2: wave = 4 edge-slots x 16 feature-groups. srcw fetched 64-at-a-time
// coalesced (pad-safe, no clamp), shfl broadcast; 4 gathers in flight.
// ---------------------------------------------------------------------------
__device__ __forceinline__ float fast_tanh(float x) {
    float ax = fabsf(x);
    float e  = __builtin_amdgcn_exp2f(-2.885390082f * ax);   // exp(-2|x|)
    float r  = __builtin_amdgcn_rcpf(1.0f + e);
    float t  = fmaf(-2.0f * e, r, 1.0f);                     // (1-e)/(1+e)
    return copysignf(t, x);
}

__global__ void node_kernel(const __half* __restrict__ h16,
                            const float* __restrict__ g,
                            const float* __restrict__ hist,
                            const int* __restrict__ offsets,
                            const int2* __restrict__ srcw,
                            float* __restrict__ out_nodes,
                            float* __restrict__ out_hist, int N) {
    const int lane = threadIdx.x & 63;
    const int wid  = threadIdx.x >> 6;
    const int wpb  = blockDim.x >> 6;
    const int slot = lane >> 4;      // 0..3: edge within group of 4
    const int fg   = lane & 15;      // feature group: floats fg*4 .. fg*4+3

    for (int n = blockIdx.x * wpb + wid; n < N; n += gridDim.x * wpb) {
        const int beg = offsets[n];
        const int end = offsets[n + 1];
        const float4 gd = *reinterpret_cast<const float4*>(
            g + (size_t)n * D_FEAT + fg * 4);

        float4 acc = make_float4(0.0f, 0.0f, 0.0f, 0.0f);

        for (int base = beg; base < end; base += 64) {
            const int chunk = min(64, end - base);
            // coalesced chunk load; srcw[E..E+64) is zeroed padding
            const int2 my_sw = srcw[base + lane];

            for (int g0 = 0; g0 < chunk; g0 += 16) {
                const int i0 = g0 + slot;
                const int i1 = i0 + 4;
                const int i2 = i0 + 8;
                const int i3 = i0 + 12;
                const int   s0 = __shfl(my_sw.x, i0, 64);
                const float w0 = __int_as_float(__shfl(my_sw.y, i0, 64));
                const int   s1 = __shfl(my_sw.x, i1, 64);
                const float w1 = __int_as_float(__shfl(my_sw.y, i1, 64));
                const int   s2 = __shfl(my_sw.x, i2, 64);
                const float w2 = __int_as_float(__shfl(my_sw.y, i2, 64));
                const int   s3 = __shfl(my_sw.x, i3, 64);
                const float w3 = __int_as_float(__shfl(my_sw.y, i3, 64));

                // four independent gathers in flight
                const uint2 h0 = *reinterpret_cast<const uint2*>(
                    h16 + (size_t)s0 * D_FEAT + fg * 4);
                const uint2 h1 = *reinterpret_cast<const uint2*>(
                    h16 + (size_t)s1 * D_FEAT + fg * 4);
                const uint2 h2 = *reinterpret_cast<const uint2*>(
                    h16 + (size_t)s2 * D_FEAT + fg * 4);
                const uint2 h3 = *reinterpret_cast<const uint2*>(
                    h16 + (size_t)s3 * D_FEAT + fg * 4);

                const float m0 = (i0 < chunk) ? 1.0f : 0.0f;
                const float m1 = (i1 < chunk) ? 1.0f : 0.0f;
                const float m2 = (i2 < chunk) ? 1.0f : 0.0f;
                const float m3 = (i3 < chunk) ? 1.0f : 0.0f;

                {
                    const float2 a0 = __half22float2(
                        *reinterpret_cast<const __half2*>(&h0.x));
                    const float2 a1 = __half22float2(
                        *reinterpret_cast<const __half2*>(&h0.y));
                    acc.x = fmaf(m0, fast_tanh(fmaf(gd.x, w0, a0.x)), acc.x);
                    acc.y = fmaf(m0, fast_tanh(fmaf(gd.y, w0, a0.y)), acc.y);
                    acc.z = fmaf(m0, fast_tanh(fmaf(gd.z, w0, a1.x)), acc.z);
                    acc.w = fmaf(m0, fast_tanh(fmaf(gd.w, w0, a1.y)), acc.w);
                }
                {
                    const float2 a0 = __half22float2(
                        *reinterpret_cast<const __half2*>(&h1.x));
                    const float2 a1 = __half22float2(
                        *reinterpret_cast<const __half2*>(&h1.y));
                    acc.x = fmaf(m1, fast_tanh(fmaf(gd.x, w1, a0.x)), acc.x);
                    acc.y = fmaf(m1, fast_tanh(fmaf(gd.y, w1, a0.y)), acc.y);
                    acc.z = fmaf(m1, fast_tanh(fmaf(gd.z, w1, a1.x)), acc.z);
                    acc.w = fmaf(m1, fast_tanh(fmaf(gd.w, w1, a1.y)), acc.w);
                }
                {
                    const float2 a0 = __half22float2(
                        *reinterpret_cast<const __half2*>(&h2.x));
                    const float2 a1 = __half22float2(
                        *reinterpret_cast<const __half2*>(&h2.y));
                    acc.x = fmaf(m2, fast_tanh(fmaf(gd.x, w2, a0.x)), acc.x);
                    acc.y = fmaf(m2, fast_tanh(fmaf(gd.y, w2, a0.y)), acc.y);
                    acc.z = fmaf(m2, fast_tanh(fmaf(gd.z, w2, a1.x)), acc.z);
                    acc.w = fmaf(m2, fast_tanh(fmaf(gd.w, w2, a1.y)), acc.w);
                }
                {
                    const float2 a0 = __half22float2(
                        *reinterpret_cast<const __half2*>(&h3.x));
                    const float2 a1 = __half22float2(
                        *reinterpret_cast<const __half2*>(&h3.y));
                    acc.x = fmaf(m3, fast_tanh(fmaf(gd.x, w3, a0.x)), acc.x);
                    acc.y = fmaf(m3, fast_tanh(fmaf(gd.y, w3, a0.y)), acc.y);
                    acc.z = fmaf(m3, fast_tanh(fmaf(gd.z, w3, a1.x)), acc.z);
                    acc.w = fmaf(m3, fast_tanh(fmaf(gd.w, w3, a1.y)), acc.w);
                }
            }
        }

        // combine the 4 slots (lanes differing in bits 4 and 5)
        acc.x += __shfl_xor(acc.x, 16, 64);
        acc.y += __shfl_xor(acc.y, 16, 64);
        acc.z += __shfl_xor(acc.z, 16, 64);
        acc.w += __shfl_xor(acc.w, 16, 64);
        acc.x += __shfl_xor(acc.x, 32, 64);
        acc.y += __shfl_xor(acc.y, 32, 64);
        acc.z += __shfl_xor(acc.z, 32, 64);
        acc.w += __shfl_xor(acc.w, 32, 64);

        if (lane < 16) {
            const float4 hv4 = *reinterpret_cast<const float4*>(
                hist + (size_t)n * D_FEAT + fg * 4);
            reinterpret_cast<float4*>(out_nodes + (size_t)n * D_FEAT)[fg] = acc;
            float4 o;
            o.x = acc.x + hv4.x;
            o.y = acc.y + hv4.y;
            o.z = acc.z + hv4.z;
            o.w = acc.w + hv4.w;
            reinterpret_cast<float4*>(out_hist + (size_t)n * D_FEAT)[fg] = o;
        }
    }
}

extern "C" void kernel_launch(void* const* d_in, const int* in_sizes, int n_in,
                              void* d_out, int out_size, void* d_ws, size_t ws_size,
                              hipStream_t stream) {
    const float* old_g = (const float*)d_in[0];
    const float* W     = (const float*)d_in[1];
    const float* ew    = (const float*)d_in[2];
    const float* hist  = (const float*)d_in[3];
    const int*   src   = (const int*)d_in[4];
    const int*   dst   = (const int*)d_in[5];

    const int N  = in_sizes[0] / D_FEAT;
    const int E  = in_sizes[4];
    const int ND = N * D_FEAT;
    const int npp = (N + NPART - 1) / NPART;

    float* out_nodes = (float*)d_out;
    float* out_hist  = (float*)d_out + ND;

    // Workspace layout
    char* ws = (char*)d_ws;
    __half* h16     = (__half*)ws;                     ws += (size_t)ND * 4;
    int*   cnt      = (int*)ws;                        ws += (size_t)N * 4;
    int*   offsets  = (int*)ws;                        ws += (size_t)(N + 2) * 4;
    int*   cursor   = (int*)ws;                        ws += (size_t)N * 4;
    int*   blockSums= (int*)ws;                        ws += 1024 * 4;
    ws = (char*)(((uintptr_t)ws + 7) & ~(uintptr_t)7);
    int2*  srcw     = (int2*)ws;   // E entries + 64 zeroed pad

    const int nb = (N + SCAN_CHUNK - 1) / SCAN_CHUNK;

    hipMemsetAsync(cnt, 0, (size_t)N * sizeof(int), stream);
    hipMemsetAsync(srcw + E, 0, 64 * sizeof(int2), stream);  // node pad

    // K1: h = old_g @ W (LDS-tiled, fp16 output)
    {
        int grid = (N + GR - 1) / GR;
        gemm64_tile_kernel<<<grid, 256, 0, stream>>>(old_g, W, h16, N);
    }

    // CSR build (XCD-partitioned hist + fill)
    hist_kernel<<<2048, 256, 0, stream>>>(dst, cnt, E, npp);
    block_sum_kernel<<<nb, SCAN_BLK, 0, stream>>>(cnt, N, blockSums);
    top_scan_kernel<<<1, 64, 0, stream>>>(blockSums, nb);
    scan_fill_kernel<<<nb, SCAN_BLK, 0, stream>>>(cnt, N, blockSums, offsets,
                                                  cursor, E);
    fill_kernel<<<2048, 256, 0, stream>>>(src, dst, ew, cursor, srcw, E, npp);

    // K2: per-node accumulation + fused history
    {
        const int block = 256, wpb = block / 64;
        int grid = (N + wpb - 1) / wpb;
        if (grid > 8192) grid = 8192;
        node_kernel<<<grid, block, 0, stream>>>(h16, old_g, hist, offsets, srcw,
                                                out_nodes, out_hist, N);
    }
}

// Round 17
// 204.850 us; speedup vs baseline: 4.0144x; 1.0858x over previous
//
#include <hip/hip_runtime.h>
#include <hip/hip_bf16.h>
#include <hip/hip_fp16.h>

// N = 100000 nodes, D = 64 features, E = 1250000 edges.
// Inputs: old_g[N,D] f32, W[D,D] f32, edge_weight[E,1] f32,
//         history_db[N,D] f32, src[E] i32, dst[E] i32
// Output: concat(nodes_new[N,D], history_new[N,D]) f32.
//
// Pipeline (R11 structure + packed 4B edge payload):
//  (1) LDS-tiled fp32 GEMM h = old_g @ W, stored fp16;
//  (2) CSR-by-dst build, XCD-partitioned hist + fill; payload packed to
//      uint32 {src:17 | wq:15} (15-bit weight, err<=1.5e-5) -> scatter
//      bytes halved;
//  (3) node kernel (R11 form: 2 gathers in flight, clamped chunk load,
//      VGPR~32/occ 66% -- R14 showed 4-deep unroll costs occupancy):
//      wave = 4 edge-slots x 16 feature-groups, coalesced srcw chunk load
//      + shfl broadcast, shfl_xor slot-reduce, fused history output.

#define D_FEAT 64
#define SCAN_BLK 256
#define SCAN_CHUNK 1024   // 4 elements per thread
#define NPART 8           // = #XCDs; blockIdx%8 ~ XCD (round-robin dispatch)
#define WQ_SCALE 32767.0f
#define WQ_INV   (1.0f / 32767.0f)

// ---------------------------------------------------------------------------
// K1: h = old_g @ W.  Block = 256 threads -> 128-row x 64-col tile.
// ---------------------------------------------------------------------------
#define GR 128
#define GPAD 66

__global__ __launch_bounds__(256) void gemm64_tile_kernel(
    const float* __restrict__ g, const float* __restrict__ W,
    __half* __restrict__ h16, int N) {
    __shared__ float Wl[D_FEAT * D_FEAT];
    __shared__ float Gl[GR][GPAD];

    const int tid = threadIdx.x;

    {
        const float4* w4 = reinterpret_cast<const float4*>(W);
        float4* wl4 = reinterpret_cast<float4*>(Wl);
        for (int i = tid; i < D_FEAT * D_FEAT / 4; i += 256) wl4[i] = w4[i];
    }

    const int row0  = blockIdx.x * GR;
    const int nrows = min(GR, N - row0);

    for (int i = tid; i < GR * 16; i += 256) {
        const int r  = i >> 4;
        const int c4 = i & 15;
        if (r < nrows) {
            float4 v = reinterpret_cast<const float4*>(
                           g + (size_t)(row0 + r) * D_FEAT)[c4];
            float* dp = &Gl[r][c4 * 4];
            reinterpret_cast<float2*>(dp)[0] = make_float2(v.x, v.y);
            reinterpret_cast<float2*>(dp)[1] = make_float2(v.z, v.w);
        }
    }
    __syncthreads();

    const int cg = tid & 7;
    const int rg = tid >> 3;
    const int c0 = cg * 8;
    const int r0 = rg * 4;

    float acc[4][8];
#pragma unroll
    for (int i = 0; i < 4; ++i)
#pragma unroll
        for (int j = 0; j < 8; ++j) acc[i][j] = 0.0f;

#pragma unroll 4
    for (int k = 0; k < D_FEAT; ++k) {
        const float4 wa = *reinterpret_cast<const float4*>(&Wl[k * D_FEAT + c0]);
        const float4 wb = *reinterpret_cast<const float4*>(&Wl[k * D_FEAT + c0 + 4]);
        float gv[4];
#pragma unroll
        for (int i = 0; i < 4; ++i) gv[i] = Gl[r0 + i][k];
#pragma unroll
        for (int i = 0; i < 4; ++i) {
            acc[i][0] = fmaf(gv[i], wa.x, acc[i][0]);
            acc[i][1] = fmaf(gv[i], wa.y, acc[i][1]);
            acc[i][2] = fmaf(gv[i], wa.z, acc[i][2]);
            acc[i][3] = fmaf(gv[i], wa.w, acc[i][3]);
            acc[i][4] = fmaf(gv[i], wb.x, acc[i][4]);
            acc[i][5] = fmaf(gv[i], wb.y, acc[i][5]);
            acc[i][6] = fmaf(gv[i], wb.z, acc[i][6]);
            acc[i][7] = fmaf(gv[i], wb.w, acc[i][7]);
        }
    }

#pragma unroll
    for (int i = 0; i < 4; ++i) {
        const int r = r0 + i;
        if (r < nrows) {
            __half2 hb[4];
#pragma unroll
            for (int j = 0; j < 4; ++j)
                hb[j] = __floats2half2_rn(acc[i][2 * j], acc[i][2 * j + 1]);
            *reinterpret_cast<uint4*>(h16 + (size_t)(row0 + r) * D_FEAT + c0) =
                *reinterpret_cast<uint4*>(hb);
        }
    }
}

// ---------------------------------------------------------------------------
// CSR build — XCD-partitioned by dst range.
// ---------------------------------------------------------------------------
__global__ void hist_kernel(const int* __restrict__ dst, int* __restrict__ cnt,
                            int E, int npp) {
    const int part = blockIdx.x & (NPART - 1);
    const int lo = part * npp;
    const int hi = lo + npp;
    const int bid = blockIdx.x >> 3;
    const int nb  = gridDim.x >> 3;
    const int E4 = E >> 2;
    const int4* dst4 = reinterpret_cast<const int4*>(dst);

    int i = bid * blockDim.x + threadIdx.x;
    const int stride = nb * blockDim.x;
    for (; i < E4; i += stride) {
        int4 d = dst4[i];
        if (d.x >= lo && d.x < hi) atomicAdd(&cnt[d.x], 1);
        if (d.y >= lo && d.y < hi) atomicAdd(&cnt[d.y], 1);
        if (d.z >= lo && d.z < hi) atomicAdd(&cnt[d.z], 1);
        if (d.w >= lo && d.w < hi) atomicAdd(&cnt[d.w], 1);
    }
    for (int e = E4 * 4 + bid * blockDim.x + threadIdx.x; e < E;
         e += nb * blockDim.x) {
        int d = dst[e];
        if (d >= lo && d < hi) atomicAdd(&cnt[d], 1);
    }
}

__global__ void block_sum_kernel(const int* __restrict__ cnt, int n,
                                 int* __restrict__ blockSums) {
    __shared__ int lds[SCAN_BLK];
    const int base = blockIdx.x * SCAN_CHUNK;
    const int t = threadIdx.x;
    int s = 0;
#pragma unroll
    for (int i = 0; i < 4; ++i) {
        int idx = base + t * 4 + i;
        s += (idx < n) ? cnt[idx] : 0;
    }
    lds[t] = s;
    __syncthreads();
    for (int off = SCAN_BLK / 2; off > 0; off >>= 1) {
        if (t < off) lds[t] += lds[t + off];
        __syncthreads();
    }
    if (t == 0) blockSums[blockIdx.x] = lds[0];
}

__global__ void top_scan_kernel(int* __restrict__ blockSums, int nb) {
    if (threadIdx.x == 0 && blockIdx.x == 0) {
        int acc = 0;
        for (int i = 0; i < nb; ++i) {
            int v = blockSums[i];
            blockSums[i] = acc;
            acc += v;
        }
    }
}

__global__ void scan_fill_kernel(const int* __restrict__ cnt, int n,
                                 const int* __restrict__ blockSums,
                                 int* __restrict__ offsets,
                                 int* __restrict__ cursor, int E) {
    __shared__ int lds[SCAN_BLK];
    const int base = blockIdx.x * SCAN_CHUNK;
    const int t = threadIdx.x;
    int v[4];
    int s = 0;
#pragma unroll
    for (int i = 0; i < 4; ++i) {
        int idx = base + t * 4 + i;
        v[i] = (idx < n) ? cnt[idx] : 0;
        s += v[i];
    }
    lds[t] = s;
    __syncthreads();
    for (int off = 1; off < SCAN_BLK; off <<= 1) {
        int x = (t >= off) ? lds[t - off] : 0;
        __syncthreads();
        lds[t] += x;
        __syncthreads();
    }
    int run = lds[t] - s + blockSums[blockIdx.x];  // exclusive prefix
#pragma unroll
    for (int i = 0; i < 4; ++i) {
        int idx = base + t * 4 + i;
        if (idx < n) {
            offsets[idx] = run;
            cursor[idx]  = run;
            run += v[i];
        }
    }
    if (blockIdx.x == 0 && t == 0) offsets[n] = E;
}

__device__ __forceinline__ unsigned pack_edge(int s, float w) {
    int wq = __float2int_rn(w * WQ_SCALE);
    wq = min(wq, 32767);
    wq = max(wq, 0);
    return (unsigned)s | ((unsigned)wq << 17);
}

__global__ void fill_kernel(const int* __restrict__ src,
                            const int* __restrict__ dst,
                            const float* __restrict__ ew,
                            int* __restrict__ cursor,
                            unsigned* __restrict__ srcw, int E, int npp) {
    const int part = blockIdx.x & (NPART - 1);
    const int lo = part * npp;
    const int hi = lo + npp;
    const int bid = blockIdx.x >> 3;
    const int nb  = gridDim.x >> 3;
    const int E4 = E >> 2;
    const int4* dst4 = reinterpret_cast<const int4*>(dst);

    int i = bid * blockDim.x + threadIdx.x;
    const int stride = nb * blockDim.x;
    for (; i < E4; i += stride) {
        int4 d = dst4[i];
        const int e = i * 4;
        if (d.x >= lo && d.x < hi) {
            int pos = atomicAdd(&cursor[d.x], 1);
            srcw[pos] = pack_edge(src[e + 0], ew[e + 0]);
        }
        if (d.y >= lo && d.y < hi) {
            int pos = atomicAdd(&cursor[d.y], 1);
            srcw[pos] = pack_edge(src[e + 1], ew[e + 1]);
        }
        if (d.z >= lo && d.z < hi) {
            int pos = atomicAdd(&cursor[d.z], 1);
            srcw[pos] = pack_edge(src[e + 2], ew[e + 2]);
        }
        if (d.w >= lo && d.w < hi) {
            int pos = atomicAdd(&cursor[d.w], 1);
            srcw[pos] = pack_edge(src[e + 3], ew[e + 3]);
        }
    }
    for (int e = E4 * 4 + bid * blockDim.x + threadIdx.x; e < E;
         e += nb * blockDim.x) {
        int d = dst[e];
        if (d >= lo && d < hi) {
            int pos = atomicAdd(&cursor[d], 1);
            srcw[pos] = pack_edge(src[e], ew[e]);
        }
    }
}

// ---------------------------------------------------------------------------
// K2: wave = 4 edge-slots x 16 feature-groups (R11 form). srcw fetched
// 64-at-a-time coalesced (clamped), one shfl per edge; 2 gathers in flight.
// ---------------------------------------------------------------------------
__device__ __forceinline__ float fast_tanh(float x) {
    float ax = fabsf(x);
    float e  = __builtin_amdgcn_exp2f(-2.885390082f * ax);   // exp(-2|x|)
    float r  = __builtin_amdgcn_rcpf(1.0f + e);
    float t  = fmaf(-2.0f * e, r, 1.0f);                     // (1-e)/(1+e)
    return copysignf(t, x);
}

__global__ void node_kernel(const __half* __restrict__ h16,
                            const float* __restrict__ g,
                            const float* __restrict__ hist,
                            const int* __restrict__ offsets,
                            const unsigned* __restrict__ srcw,
                            float* __restrict__ out_nodes,
                            float* __restrict__ out_hist, int N) {
    const int lane = threadIdx.x & 63;
    const int wid  = threadIdx.x >> 6;
    const int wpb  = blockDim.x >> 6;
    const int slot = lane >> 4;      // 0..3: edge within group of 4
    const int fg   = lane & 15;      // feature group: floats fg*4 .. fg*4+3

    for (int n = blockIdx.x * wpb + wid; n < N; n += gridDim.x * wpb) {
        const int beg = offsets[n];
        const int end = offsets[n + 1];
        const float4 gd = *reinterpret_cast<const float4*>(
            g + (size_t)n * D_FEAT + fg * 4);

        float4 acc = make_float4(0.0f, 0.0f, 0.0f, 0.0f);

        for (int base = beg; base < end; base += 64) {
            const int chunk = min(64, end - base);
            // one coalesced load: lane l holds srcw[base+l] (clamped)
            const unsigned my_sw = srcw[base + min(lane, chunk - 1)];

            for (int g0 = 0; g0 < chunk; g0 += 8) {
                const int ia = g0 + slot;
                const int ib = ia + 4;
                const unsigned pa = (unsigned)__shfl((int)my_sw, ia, 64);
                const unsigned pb = (unsigned)__shfl((int)my_sw, ib, 64);
                const int   sa = pa & 0x1FFFF;
                const float wa = (float)(pa >> 17) * WQ_INV;
                const int   sb = pb & 0x1FFFF;
                const float wb = (float)(pb >> 17) * WQ_INV;
                const bool va = ia < chunk;
                const bool vb = ib < chunk;
                // both gathers issued before either consumed
                const uint2 hva = *reinterpret_cast<const uint2*>(
                    h16 + (size_t)sa * D_FEAT + fg * 4);
                const uint2 hvb = *reinterpret_cast<const uint2*>(
                    h16 + (size_t)sb * D_FEAT + fg * 4);

                const float2 a0 = __half22float2(
                    *reinterpret_cast<const __half2*>(&hva.x));
                const float2 a1 = __half22float2(
                    *reinterpret_cast<const __half2*>(&hva.y));
                const float ma = va ? 1.0f : 0.0f;
                acc.x = fmaf(ma, fast_tanh(fmaf(gd.x, wa, a0.x)), acc.x);
                acc.y = fmaf(ma, fast_tanh(fmaf(gd.y, wa, a0.y)), acc.y);
                acc.z = fmaf(ma, fast_tanh(fmaf(gd.z, wa, a1.x)), acc.z);
                acc.w = fmaf(ma, fast_tanh(fmaf(gd.w, wa, a1.y)), acc.w);

                const float2 b0 = __half22float2(
                    *reinterpret_cast<const __half2*>(&hvb.x));
                const float2 b1 = __half22float2(
                    *reinterpret_cast<const __half2*>(&hvb.y));
                const float mb = vb ? 1.0f : 0.0f;
                acc.x = fmaf(mb, fast_tanh(fmaf(gd.x, wb, b0.x)), acc.x);
                acc.y = fmaf(mb, fast_tanh(fmaf(gd.y, wb, b0.y)), acc.y);
                acc.z = fmaf(mb, fast_tanh(fmaf(gd.z, wb, b1.x)), acc.z);
                acc.w = fmaf(mb, fast_tanh(fmaf(gd.w, wb, b1.y)), acc.w);
            }
        }

        // combine the 4 slots (lanes differing in bits 4 and 5)
        acc.x += __shfl_xor(acc.x, 16, 64);
        acc.y += __shfl_xor(acc.y, 16, 64);
        acc.z += __shfl_xor(acc.z, 16, 64);
        acc.w += __shfl_xor(acc.w, 16, 64);
        acc.x += __shfl_xor(acc.x, 32, 64);
        acc.y += __shfl_xor(acc.y, 32, 64);
        acc.z += __shfl_xor(acc.z, 32, 64);
        acc.w += __shfl_xor(acc.w, 32, 64);

        if (lane < 16) {
            const float4 hv4 = *reinterpret_cast<const float4*>(
                hist + (size_t)n * D_FEAT + fg * 4);
            reinterpret_cast<float4*>(out_nodes + (size_t)n * D_FEAT)[fg] = acc;
            float4 o;
            o.x = acc.x + hv4.x;
            o.y = acc.y + hv4.y;
            o.z = acc.z + hv4.z;
            o.w = acc.w + hv4.w;
            reinterpret_cast<float4*>(out_hist + (size_t)n * D_FEAT)[fg] = o;
        }
    }
}

extern "C" void kernel_launch(void* const* d_in, const int* in_sizes, int n_in,
                              void* d_out, int out_size, void* d_ws, size_t ws_size,
                              hipStream_t stream) {
    const float* old_g = (const float*)d_in[0];
    const float* W     = (const float*)d_in[1];
    const float* ew    = (const float*)d_in[2];
    const float* hist  = (const float*)d_in[3];
    const int*   src   = (const int*)d_in[4];
    const int*   dst   = (const int*)d_in[5];

    const int N  = in_sizes[0] / D_FEAT;
    const int E  = in_sizes[4];
    const int ND = N * D_FEAT;
    const int npp = (N + NPART - 1) / NPART;

    float* out_nodes = (float*)d_out;
    float* out_hist  = (float*)d_out + ND;

    // Workspace layout
    char* ws = (char*)d_ws;
    __half* h16     = (__half*)ws;                     ws += (size_t)ND * 2;
    int*   cnt      = (int*)ws;                        ws += (size_t)N * 4;
    int*   offsets  = (int*)ws;                        ws += (size_t)(N + 2) * 4;
    int*   cursor   = (int*)ws;                        ws += (size_t)N * 4;
    int*   blockSums= (int*)ws;                        ws += 1024 * 4;
    unsigned* srcw  = (unsigned*)ws;                   // E entries (4B each)

    const int nb = (N + SCAN_CHUNK - 1) / SCAN_CHUNK;

    hipMemsetAsync(cnt, 0, (size_t)N * sizeof(int), stream);

    // K1: h = old_g @ W (LDS-tiled, fp16 output)
    {
        int grid = (N + GR - 1) / GR;
        gemm64_tile_kernel<<<grid, 256, 0, stream>>>(old_g, W, h16, N);
    }

    // CSR build (XCD-partitioned hist + fill, packed payload)
    hist_kernel<<<2048, 256, 0, stream>>>(dst, cnt, E, npp);
    block_sum_kernel<<<nb, SCAN_BLK, 0, stream>>>(cnt, N, blockSums);
    top_scan_kernel<<<1, 64, 0, stream>>>(blockSums, nb);
    scan_fill_kernel<<<nb, SCAN_BLK, 0, stream>>>(cnt, N, blockSums, offsets,
                                                  cursor, E);
    fill_kernel<<<2048, 256, 0, stream>>>(src, dst, ew, cursor, srcw, E, npp);

    // K2: per-node accumulation + fused history
    {
        const int block = 256, wpb = block / 64;
        int grid = (N + wpb - 1) / wpb;
        if (grid > 8192) grid = 8192;
        node_kernel<<<grid, block, 0, stream>>>(h16, old_g, hist, offsets, srcw,
                                                out_nodes, out_hist, N);
    }
}